// Round 1
// baseline (1096.607 us; speedup 1.0000x reference)
//
#include <hip/hip_runtime.h>

#define SEQ    2048
#define BATCH  16
#define HID    1024
#define M_TOT  (SEQ*BATCH)      // 32768 rows
#define NCH    (BATCH*HID)      // 16384 scan channels
#define NCHUNK 32
#define TCHUNK (SEQ/NCHUNK)     // 64 timesteps per chunk

typedef __attribute__((ext_vector_type(8))) short  short8;
typedef __attribute__((ext_vector_type(4))) float  floatx4;

__device__ __forceinline__ unsigned short f32_to_bf16(float f) {
  unsigned int u = __float_as_uint(f);
  u += 0x7FFFu + ((u >> 16) & 1u);           // round-to-nearest-even
  return (unsigned short)(u >> 16);
}
__device__ __forceinline__ float bf16_to_f32(unsigned short h) {
  return __uint_as_float(((unsigned int)h) << 16);
}
__device__ __forceinline__ float sigmoidf_(float x) {
  return 1.f / (1.f + __expf(-x));
}

#define LDS_DMA16(gp, lp) \
  __builtin_amdgcn_global_load_lds((const __attribute__((address_space(1))) void*)(gp), \
                                   (__attribute__((address_space(3))) void*)(lp), 16, 0, 0)

// ---------------------------------------------------------------- cast x -> bf16
__global__ void cast_f32_bf16(const float* __restrict__ in, unsigned short* __restrict__ out, int n4) {
  int i = blockIdx.x * blockDim.x + threadIdx.x;
  if (i >= n4) return;
  float4 v = ((const float4*)in)[i];
  ushort4 o;
  o.x = f32_to_bf16(v.x); o.y = f32_to_bf16(v.y);
  o.z = f32_to_bf16(v.z); o.w = f32_to_bf16(v.w);
  ((ushort4*)out)[i] = o;
}

// ------------------------------------------- W (rows x cols) fp32 -> Wt (cols x rows) bf16
__global__ void transpose_cast(const float* __restrict__ W, unsigned short* __restrict__ Wt,
                               int rows, int cols) {
  __shared__ float tile[32][33];
  int c0 = blockIdx.x * 32, r0 = blockIdx.y * 32;
  int tx = threadIdx.x, ty = threadIdx.y;
  for (int i = ty; i < 32; i += 8)
    tile[i][tx] = W[(size_t)(r0 + i) * cols + c0 + tx];
  __syncthreads();
  for (int i = ty; i < 32; i += 8)
    Wt[(size_t)(c0 + i) * rows + r0 + tx] = f32_to_bf16(tile[tx][i]);
}

// ---------------------------------------------------------------- bf16 MFMA GEMM
// A: (M,K) bf16 row-major.  Bt: (N,K) bf16 row-major (W transposed).
// Output column j: j<1024 -> Xt fp32 (x_tilde); 1024<=j<2048 -> F = sigmoid(u+bias[j-1024]) bf16;
// j>=2048 -> R = sigmoid(u+bias[j-1024]) bf16.  Tiles: BM=BN=128, BK=32, 4 waves of 64x64.
__global__ __launch_bounds__(256) void gemm_bt_fused(
    const unsigned short* __restrict__ A, const unsigned short* __restrict__ Bt,
    float* __restrict__ Xt, unsigned short* __restrict__ Fo, unsigned short* __restrict__ Ro,
    const float* __restrict__ bias, int K)
{
  __shared__ __align__(16) unsigned short As[128 * 32];
  __shared__ __align__(16) unsigned short Bs[128 * 32];
  const int tid  = threadIdx.x;
  const int wave = tid >> 6, lane = tid & 63;
  const int bn = blockIdx.x, bm = blockIdx.y;
  const int wm = wave >> 1, wn = wave & 1;

  // staging: 16 chunks of 1KB (16 rows x 64B); wave w loads chunks {2w,2w+1} of As and Bs
  const int c0 = wave * 2, c1 = wave * 2 + 1;
  const int lr = lane >> 2;          // row within chunk 0..15
  const int lc = (lane & 3) * 8;     // k-element offset (16B per lane)
  const unsigned short* gA0 = A  + (size_t)(bm * 128 + c0 * 16 + lr) * K + lc;
  const unsigned short* gA1 = A  + (size_t)(bm * 128 + c1 * 16 + lr) * K + lc;
  const unsigned short* gB0 = Bt + (size_t)(bn * 128 + c0 * 16 + lr) * K + lc;
  const unsigned short* gB1 = Bt + (size_t)(bn * 128 + c1 * 16 + lr) * K + lc;
  unsigned short* lA0 = As + c0 * 512;
  unsigned short* lA1 = As + c1 * 512;
  unsigned short* lB0 = Bs + c0 * 512;
  unsigned short* lB1 = Bs + c1 * 512;

  floatx4 acc[4][4];
#pragma unroll
  for (int i = 0; i < 4; i++)
#pragma unroll
    for (int j = 0; j < 4; j++)
#pragma unroll
      for (int r = 0; r < 4; r++) acc[i][j][r] = 0.f;

  const int ar  = wm * 64 + (lane & 15);   // A fragment m-row in LDS tile
  const int brr = wn * 64 + (lane & 15);   // B fragment n-row in LDS tile
  const int kk  = (lane >> 4) * 8;         // k offset within BK

  for (int kt = 0; kt < K; kt += 32) {
    __syncthreads();                       // previous compute done with LDS
    LDS_DMA16(gA0, lA0);
    LDS_DMA16(gA1, lA1);
    LDS_DMA16(gB0, lB0);
    LDS_DMA16(gB1, lB1);
    gA0 += 32; gA1 += 32; gB0 += 32; gB1 += 32;
    __syncthreads();                       // drains vmcnt -> tiles resident
    short8 a[4], b[4];
#pragma unroll
    for (int i = 0; i < 4; i++) a[i] = *(const short8*)(As + (ar + i * 16) * 32 + kk);
#pragma unroll
    for (int j = 0; j < 4; j++) b[j] = *(const short8*)(Bs + (brr + j * 16) * 32 + kk);
#pragma unroll
    for (int i = 0; i < 4; i++)
#pragma unroll
      for (int j = 0; j < 4; j++)
        acc[i][j] = __builtin_amdgcn_mfma_f32_16x16x32_bf16(a[i], b[j], acc[i][j], 0, 0, 0);
  }

  // epilogue: C/D layout col=lane&15, row=(lane>>4)*4+reg  [m89/m91-verified]
  const int row0 = bm * 128 + wm * 64 + (lane >> 4) * 4;
  const int col0 = bn * 128 + wn * 64 + (lane & 15);
#pragma unroll
  for (int i = 0; i < 4; i++) {
#pragma unroll
    for (int j = 0; j < 4; j++) {
      int gc = col0 + j * 16;
#pragma unroll
      for (int rg = 0; rg < 4; rg++) {
        int gr = row0 + i * 16 + rg;
        float u = acc[i][j][rg];
        if (gc < 1024) {
          Xt[(size_t)gr * 1024 + gc] = u;
        } else {
          float s = sigmoidf_(u + bias[gc - 1024]);
          if (gc < 2048) Fo[(size_t)gr * 1024 + (gc - 1024)] = f32_to_bf16(s);
          else           Ro[(size_t)gr * 1024 + (gc - 2048)] = f32_to_bf16(s);
        }
      }
    }
  }
}

// -------------------------------------------------- blocked scan pass 1: per-chunk (P, S)
__global__ void scan_pass1(const float* __restrict__ Xt, const unsigned short* __restrict__ F,
                           float* __restrict__ P, float* __restrict__ S) {
  int ch = blockIdx.x * blockDim.x + threadIdx.x;      // 0..16383
  int chunk = blockIdx.y;
  size_t idx = (size_t)chunk * TCHUNK * NCH + ch;
  float p = 1.f, s = 0.f;
  for (int t = 0; t < TCHUNK; ++t) {
    float f  = bf16_to_f32(F[idx]);
    float xt = Xt[idx];
    s = f * s + (1.f - f) * xt;
    p *= f;
    idx += NCH;
  }
  P[(size_t)chunk * NCH + ch] = p;
  S[(size_t)chunk * NCH + ch] = s;
}

// -------------------------------------------------- serial combine -> carry-in per chunk
__global__ void combine_c0(const float* __restrict__ P, const float* __restrict__ S,
                           float* __restrict__ C0) {
  int ch = blockIdx.x * blockDim.x + threadIdx.x;
  float c = 0.f;
  for (int k = 0; k < NCHUNK; ++k) {
    C0[(size_t)k * NCH + ch] = c;
    c = P[(size_t)k * NCH + ch] * c + S[(size_t)k * NCH + ch];
  }
}

// -------------------------------------------------- pass 2 (layer 1): emit h1 = r*c + (1-r)*x, bf16
__global__ void scan1_pass2(const float* __restrict__ Xt, const unsigned short* __restrict__ F,
                            const unsigned short* __restrict__ R, const float* __restrict__ x,
                            const float* __restrict__ C0, unsigned short* __restrict__ h1b) {
  int ch = blockIdx.x * blockDim.x + threadIdx.x;
  int chunk = blockIdx.y;
  float c = C0[(size_t)chunk * NCH + ch];
  size_t idx = (size_t)chunk * TCHUNK * NCH + ch;
  for (int t = 0; t < TCHUNK; ++t) {
    float f  = bf16_to_f32(F[idx]);
    float xt = Xt[idx];
    c = f * c + (1.f - f) * xt;
    float r  = bf16_to_f32(R[idx]);
    float xv = x[idx];
    h1b[idx] = f32_to_bf16(r * c + (1.f - r) * xv);
    idx += NCH;
  }
}

// -------------------------------------------------- r2 at last timestep only: (16x1024) @ W1[:,2048:3072]
__global__ void r2_kernel(const unsigned short* __restrict__ h1b, const float* __restrict__ W1,
                          const float* __restrict__ b1, float* __restrict__ r2) {
  __shared__ float xrow[1024];
  int b = blockIdx.x, n = threadIdx.x;
  xrow[n] = bf16_to_f32(h1b[(size_t)(2047 * 16 + b) * 1024 + n]);
  __syncthreads();
  float acc = b1[1024 + n];
  for (int d = 0; d < 1024; ++d)
    acc += xrow[d] * W1[(size_t)d * 3072 + 2048 + n];
  r2[b * 1024 + n] = sigmoidf_(acc);
}

// -------------------------------------------------- layer-2 combine + final output
__global__ void combine_final(const float* __restrict__ P, const float* __restrict__ S,
                              const float* __restrict__ r2, const unsigned short* __restrict__ h1b,
                              float* __restrict__ out) {
  int ch = blockIdx.x * blockDim.x + threadIdx.x;
  float c = 0.f;
  for (int k = 0; k < NCHUNK; ++k)
    c = P[(size_t)k * NCH + ch] * c + S[(size_t)k * NCH + ch];
  float r = r2[ch];
  float x = bf16_to_f32(h1b[(size_t)2047 * NCH + ch]);   // (2047*16+b)*1024+h == 2047*NCH+ch
  out[ch] = r * c + (1.f - r) * x;
}

extern "C" void kernel_launch(void* const* d_in, const int* in_sizes, int n_in,
                              void* d_out, int out_size, void* d_ws, size_t ws_size,
                              hipStream_t stream) {
  const float* x  = (const float*)d_in[0];
  const float* W0 = (const float*)d_in[1];
  const float* b0 = (const float*)d_in[2];
  const float* W1 = (const float*)d_in[3];
  const float* b1 = (const float*)d_in[4];
  float* out = (float*)d_out;

  char* ws = (char*)d_ws;
  auto alloc = [&](size_t bytes) {
    char* p = ws; ws += (bytes + 255) & ~(size_t)255; return p;
  };
  const size_t NE = (size_t)M_TOT * HID;               // 33,554,432
  unsigned short* xb  = (unsigned short*)alloc(NE * 2);        // x in bf16
  unsigned short* W0t = (unsigned short*)alloc((size_t)3072 * 1024 * 2);
  unsigned short* W1t = (unsigned short*)alloc((size_t)3072 * 1024 * 2);
  float*          Xt  = (float*)         alloc(NE * 4);        // x_tilde fp32 (both layers, reused)
  unsigned short* F   = (unsigned short*)alloc(NE * 2);        // f bf16 (both layers, reused)
  unsigned short* R   = (unsigned short*)alloc(NE * 2);        // r bf16 (layer 1)
  unsigned short* h1b = (unsigned short*)alloc(NE * 2);        // layer-1 output bf16
  float* P   = (float*)alloc((size_t)NCHUNK * NCH * 4);
  float* S   = (float*)alloc((size_t)NCHUNK * NCH * 4);
  float* C0  = (float*)alloc((size_t)NCHUNK * NCH * 4);
  float* r2  = (float*)alloc((size_t)NCH * 4);

  dim3 blk256(256);
  // 1. cast x -> bf16
  cast_f32_bf16<<<dim3(NE / 4 / 256), blk256, 0, stream>>>(x, xb, (int)(NE / 4));
  // 2. transpose+cast weights -> (3072,1024) bf16
  transpose_cast<<<dim3(96, 32), dim3(32, 8), 0, stream>>>(W0, W0t, 1024, 3072);
  transpose_cast<<<dim3(96, 32), dim3(32, 8), 0, stream>>>(W1, W1t, 1024, 3072);
  // 3. layer-1 GEMM (full N=3072) with fused bias+sigmoid split-store
  gemm_bt_fused<<<dim3(24, 256), blk256, 0, stream>>>(xb, W0t, Xt, F, R, b0, 1024);
  // 4. blocked scan layer 1
  scan_pass1<<<dim3(NCH / 256, NCHUNK), blk256, 0, stream>>>(Xt, F, P, S);
  combine_c0<<<dim3(NCH / 256), blk256, 0, stream>>>(P, S, C0);
  scan1_pass2<<<dim3(NCH / 256, NCHUNK), blk256, 0, stream>>>(Xt, F, R, x, C0, h1b);
  // 5. layer-2 GEMM, only x_tilde and f (N=2048); r needed only at t=2047
  gemm_bt_fused<<<dim3(16, 256), blk256, 0, stream>>>(h1b, W1t, Xt, F, R, b1, 1024);
  // 6. r2 at last timestep (16x1024 dots of length 1024, fp32 W1)
  r2_kernel<<<dim3(16), dim3(1024), 0, stream>>>(h1b, W1, b1, r2);
  // 7. blocked scan layer 2 (final c only) + output
  scan_pass1<<<dim3(NCH / 256, NCHUNK), blk256, 0, stream>>>(Xt, F, P, S);
  combine_final<<<dim3(NCH / 256), blk256, 0, stream>>>(P, S, r2, h1b, out);
}

// Round 2
// 1072.776 us; speedup vs baseline: 1.0222x; 1.0222x over previous
//
#include <hip/hip_runtime.h>

#define SEQ    2048
#define BATCH  16
#define HID    1024
#define M_TOT  (SEQ*BATCH)      // 32768 rows
#define NCH    (BATCH*HID)      // 16384 scan channels
#define NCHUNK 32
#define TCHUNK (SEQ/NCHUNK)     // 64 timesteps per chunk

typedef __attribute__((ext_vector_type(8))) short          short8;
typedef __attribute__((ext_vector_type(8))) unsigned short ushort8_t;
typedef __attribute__((ext_vector_type(4))) float          floatx4;

__device__ __forceinline__ unsigned short f32_to_bf16(float f) {
  unsigned int u = __float_as_uint(f);
  u += 0x7FFFu + ((u >> 16) & 1u);           // round-to-nearest-even
  return (unsigned short)(u >> 16);
}
__device__ __forceinline__ float bf16_to_f32(unsigned short h) {
  return __uint_as_float(((unsigned int)h) << 16);
}
__device__ __forceinline__ float sigmoidf_(float x) {
  return 1.f / (1.f + __expf(-x));
}

#define LDS_DMA16(gp, lp) \
  __builtin_amdgcn_global_load_lds((const __attribute__((address_space(1))) void*)(gp), \
                                   (__attribute__((address_space(3))) void*)(lp), 16, 0, 0)

// ============================================================================
// Swizzled operand layout ("LDS image"):
//   matrix (R rows, K cols) bf16 -> tile-blocks of 128 rows x 32 k = 4096 ushorts.
//   block index = mtile*(K/32) + ktile.  Within a block, unit u (16 B = 8 bf16
//   along k) for source element (r = row&127, kk = k&31):
//     chunk c = r>>4  (0..7), lane l = ((kk>>3)<<4) | (r&15)
//     unit = c*64 + l ;  ushort offset = unit*8 + (kk&7)
//   GEMM stages chunk c contiguously (1 KB) and lane l ds_read_b128's
//   chunk*1024 + l*16 -> sequential, conflict-free, fragment-exact.
// ============================================================================

// ---------------- x (fp32 row-major) -> swizzled bf16 -----------------------
__global__ void cast_swizzle_f32(const float* __restrict__ src, unsigned short* __restrict__ dst,
                                 int K) {
  __shared__ unsigned short tile[4096];
  const int mt = blockIdx.x, kt = blockIdx.y;
  const int t = threadIdx.x;
  const int r = t >> 1, kh = (t & 1) * 16;      // this thread: 16 consecutive k
  const float* sp = src + (size_t)(mt * 128 + r) * K + kt * 32 + kh;
  float4 v0 = *(const float4*)(sp + 0);
  float4 v1 = *(const float4*)(sp + 4);
  float4 v2 = *(const float4*)(sp + 8);
  float4 v3 = *(const float4*)(sp + 12);
  ushort8_t u0, u1;
  u0[0]=f32_to_bf16(v0.x); u0[1]=f32_to_bf16(v0.y); u0[2]=f32_to_bf16(v0.z); u0[3]=f32_to_bf16(v0.w);
  u0[4]=f32_to_bf16(v1.x); u0[5]=f32_to_bf16(v1.y); u0[6]=f32_to_bf16(v1.z); u0[7]=f32_to_bf16(v1.w);
  u1[0]=f32_to_bf16(v2.x); u1[1]=f32_to_bf16(v2.y); u1[2]=f32_to_bf16(v2.z); u1[3]=f32_to_bf16(v2.w);
  u1[4]=f32_to_bf16(v3.x); u1[5]=f32_to_bf16(v3.y); u1[6]=f32_to_bf16(v3.z); u1[7]=f32_to_bf16(v3.w);
  const int c = r >> 4, lr = r & 15, q0 = kh >> 3;
  const int unit0 = c * 64 + (q0 << 4) + lr;
  *(ushort8_t*)&tile[unit0 * 8]        = u0;
  *(ushort8_t*)&tile[(unit0 + 16) * 8] = u1;
  __syncthreads();
  const size_t base = ((size_t)mt * (K >> 5) + kt) * 4096;
  *(ushort8_t*)&dst[base + t * 16]     = *(const ushort8_t*)&tile[t * 16];
  *(ushort8_t*)&dst[base + t * 16 + 8] = *(const ushort8_t*)&tile[t * 16 + 8];
}

// ---------------- row-major bf16 -> swizzled bf16 ---------------------------
__global__ void swizzle_bf16(const unsigned short* __restrict__ src, unsigned short* __restrict__ dst,
                             int K) {
  __shared__ unsigned short tile[4096];
  const int mt = blockIdx.x, kt = blockIdx.y;
  const int t = threadIdx.x;
  const int r = t >> 1, kh = (t & 1) * 16;
  const unsigned short* sp = src + (size_t)(mt * 128 + r) * K + kt * 32 + kh;
  ushort8_t u0 = *(const ushort8_t*)(sp + 0);
  ushort8_t u1 = *(const ushort8_t*)(sp + 8);
  const int c = r >> 4, lr = r & 15, q0 = kh >> 3;
  const int unit0 = c * 64 + (q0 << 4) + lr;
  *(ushort8_t*)&tile[unit0 * 8]        = u0;
  *(ushort8_t*)&tile[(unit0 + 16) * 8] = u1;
  __syncthreads();
  const size_t base = ((size_t)mt * (K >> 5) + kt) * 4096;
  *(ushort8_t*)&dst[base + t * 16]     = *(const ushort8_t*)&tile[t * 16];
  *(ushort8_t*)&dst[base + t * 16 + 8] = *(const ushort8_t*)&tile[t * 16 + 8];
}

// ------------- W (rows x cols) fp32 -> Wt (cols x rows) bf16 row-major ------
__global__ void transpose_cast(const float* __restrict__ W, unsigned short* __restrict__ Wt,
                               int rows, int cols) {
  __shared__ float tile[32][33];
  int c0 = blockIdx.x * 32, r0 = blockIdx.y * 32;
  int tx = threadIdx.x, ty = threadIdx.y;
  for (int i = ty; i < 32; i += 8)
    tile[i][tx] = W[(size_t)(r0 + i) * cols + c0 + tx];
  __syncthreads();
  for (int i = ty; i < 32; i += 8)
    Wt[(size_t)(c0 + i) * rows + r0 + tx] = f32_to_bf16(tile[tx][i]);
}

// ---------------------------------------------------------------- MFMA GEMM
// A: swizzled (M,K).  B: swizzled (N,K) (= W^T).  128x128x32 tiles, 4 waves.
// Column region (block-uniform): bn<8 -> Xt (bf16 x_tilde); 8<=bn<16 -> F;
// bn>=16 -> R.  Gates: sigmoid(u + bias).
__global__ __launch_bounds__(256) void gemm_sw_fused(
    const unsigned short* __restrict__ A, const unsigned short* __restrict__ B,
    unsigned short* __restrict__ Xt, unsigned short* __restrict__ Fo, unsigned short* __restrict__ Ro,
    const float* __restrict__ bias, int K)
{
  __shared__ __align__(16) unsigned short As[4096];
  __shared__ __align__(16) unsigned short Bs[4096];
  const int tid = threadIdx.x;
  const int wave = tid >> 6, lane = tid & 63;
  const int bn = blockIdx.x, bm = blockIdx.y;
  const int wm = wave >> 1, wn = wave & 1;
  const int KT = K >> 5;

  const unsigned short* gA = A + (size_t)bm * KT * 4096 + wave * 1024 + lane * 8;
  const unsigned short* gB = B + (size_t)bn * KT * 4096 + wave * 1024 + lane * 8;
  unsigned short* lA = As + wave * 1024;          // wave-uniform LDS dst (chunks 2w, 2w+1)
  unsigned short* lB = Bs + wave * 1024;

  floatx4 acc[4][4];
#pragma unroll
  for (int i = 0; i < 4; i++)
#pragma unroll
    for (int j = 0; j < 4; j++)
#pragma unroll
      for (int r = 0; r < 4; r++) acc[i][j][r] = 0.f;

  const int ra = wm * 2048 + lane * 8;            // a[i] at ra + i*512 (ushorts)
  const int rb = wn * 2048 + lane * 8;

  for (int kt = 0; kt < KT; ++kt) {
    __syncthreads();
    LDS_DMA16(gA,       lA);
    LDS_DMA16(gA + 512, lA + 512);
    LDS_DMA16(gB,       lB);
    LDS_DMA16(gB + 512, lB + 512);
    gA += 4096; gB += 4096;
    __syncthreads();
    short8 a[4], b[4];
#pragma unroll
    for (int i = 0; i < 4; i++) a[i] = *(const short8*)(As + ra + i * 512);
#pragma unroll
    for (int j = 0; j < 4; j++) b[j] = *(const short8*)(Bs + rb + j * 512);
#pragma unroll
    for (int i = 0; i < 4; i++)
#pragma unroll
      for (int j = 0; j < 4; j++)
        acc[i][j] = __builtin_amdgcn_mfma_f32_16x16x32_bf16(a[i], b[j], acc[i][j], 0, 0, 0);
  }

  // epilogue: C/D layout col=lane&15, row=(lane>>4)*4+reg  [m89/m91-verified]
  const int region = bn >> 3;                       // 0:x_tilde 1:f 2:r  (uniform)
  const int colb = (bn & 7) * 128 + wn * 64 + (lane & 15);
  const int row0 = bm * 128 + wm * 64 + ((lane >> 4) << 2);
  if (region == 0) {
#pragma unroll
    for (int i = 0; i < 4; i++)
#pragma unroll
      for (int j = 0; j < 4; j++)
#pragma unroll
        for (int rg = 0; rg < 4; rg++)
          Xt[(size_t)(row0 + i * 16 + rg) * 1024 + colb + j * 16] = f32_to_bf16(acc[i][j][rg]);
  } else {
    unsigned short* O = (region == 1) ? Fo : Ro;
    const float* bp = bias + (region - 1) * 1024;
#pragma unroll
    for (int j = 0; j < 4; j++) {
      float bb = bp[colb + j * 16];
#pragma unroll
      for (int i = 0; i < 4; i++)
#pragma unroll
        for (int rg = 0; rg < 4; rg++) {
          float s = sigmoidf_(acc[i][j][rg] + bb);
          O[(size_t)(row0 + i * 16 + rg) * 1024 + colb + j * 16] = f32_to_bf16(s);
        }
    }
  }
}

// -------------------------------------------------- blocked scan pass 1
__global__ void scan_pass1(const unsigned short* __restrict__ Xt, const unsigned short* __restrict__ F,
                           float* __restrict__ P, float* __restrict__ S) {
  int ch = blockIdx.x * blockDim.x + threadIdx.x;
  int chunk = blockIdx.y;
  size_t idx = (size_t)chunk * TCHUNK * NCH + ch;
  float p = 1.f, s = 0.f;
  for (int t = 0; t < TCHUNK; ++t) {
    float f  = bf16_to_f32(F[idx]);
    float xt = bf16_to_f32(Xt[idx]);
    s = f * s + (1.f - f) * xt;
    p *= f;
    idx += NCH;
  }
  P[(size_t)chunk * NCH + ch] = p;
  S[(size_t)chunk * NCH + ch] = s;
}

// -------------------------------------------------- serial combine -> carries
__global__ void combine_c0(const float* __restrict__ P, const float* __restrict__ S,
                           float* __restrict__ C0) {
  int ch = blockIdx.x * blockDim.x + threadIdx.x;
  float c = 0.f;
  for (int k = 0; k < NCHUNK; ++k) {
    C0[(size_t)k * NCH + ch] = c;
    c = P[(size_t)k * NCH + ch] * c + S[(size_t)k * NCH + ch];
  }
}

// -------------------- pass 2 (layer 1): h1 = r*c + (1-r)*x, row-major bf16 --
__global__ void scan1_pass2(const unsigned short* __restrict__ Xt, const unsigned short* __restrict__ F,
                            const unsigned short* __restrict__ R, const float* __restrict__ x,
                            const float* __restrict__ C0, unsigned short* __restrict__ h1b) {
  int ch = blockIdx.x * blockDim.x + threadIdx.x;
  int chunk = blockIdx.y;
  float c = C0[(size_t)chunk * NCH + ch];
  size_t idx = (size_t)chunk * TCHUNK * NCH + ch;
  for (int t = 0; t < TCHUNK; ++t) {
    float f  = bf16_to_f32(F[idx]);
    float xt = bf16_to_f32(Xt[idx]);
    c = f * c + (1.f - f) * xt;
    float r  = bf16_to_f32(R[idx]);
    float xv = x[idx];
    h1b[idx] = f32_to_bf16(r * c + (1.f - r) * xv);
    idx += NCH;
  }
}

// ------------- r2 at last timestep: (16x1024) @ W1[:,2048:3072] fp32 --------
__global__ void r2_kernel(const unsigned short* __restrict__ h1b, const float* __restrict__ W1,
                          const float* __restrict__ b1, float* __restrict__ r2) {
  __shared__ float xrow[1024];
  int b = blockIdx.x, n = threadIdx.x;
  xrow[n] = bf16_to_f32(h1b[(size_t)(2047 * 16 + b) * 1024 + n]);
  __syncthreads();
  float acc = b1[1024 + n];
  for (int d = 0; d < 1024; ++d)
    acc += xrow[d] * W1[(size_t)d * 3072 + 2048 + n];
  r2[b * 1024 + n] = sigmoidf_(acc);
}

// -------------------------------------------------- layer-2 combine + output
__global__ void combine_final(const float* __restrict__ P, const float* __restrict__ S,
                              const float* __restrict__ r2, const unsigned short* __restrict__ h1b,
                              float* __restrict__ out) {
  int ch = blockIdx.x * blockDim.x + threadIdx.x;
  float c = 0.f;
  for (int k = 0; k < NCHUNK; ++k)
    c = P[(size_t)k * NCH + ch] * c + S[(size_t)k * NCH + ch];
  float r = r2[ch];
  float x = bf16_to_f32(h1b[(size_t)2047 * NCH + ch]);
  out[ch] = r * c + (1.f - r) * x;
}

extern "C" void kernel_launch(void* const* d_in, const int* in_sizes, int n_in,
                              void* d_out, int out_size, void* d_ws, size_t ws_size,
                              hipStream_t stream) {
  const float* x  = (const float*)d_in[0];
  const float* W0 = (const float*)d_in[1];
  const float* b0 = (const float*)d_in[2];
  const float* W1 = (const float*)d_in[3];
  const float* b1 = (const float*)d_in[4];
  float* out = (float*)d_out;

  char* ws = (char*)d_ws;
  auto alloc = [&](size_t bytes) {
    char* p = ws; ws += (bytes + 255) & ~(size_t)255; return p;
  };
  const size_t NE = (size_t)M_TOT * HID;
  unsigned short* xsw  = (unsigned short*)alloc(NE * 2);             // x swizzled bf16
  unsigned short* W0t  = (unsigned short*)alloc((size_t)3072 * 1024 * 2);
  unsigned short* W0sw = (unsigned short*)alloc((size_t)3072 * 1024 * 2);
  unsigned short* W1t  = (unsigned short*)alloc((size_t)3072 * 1024 * 2);
  unsigned short* W1sw = (unsigned short*)alloc((size_t)3072 * 1024 * 2);
  unsigned short* Xt   = (unsigned short*)alloc(NE * 2);             // x_tilde bf16 (reused L1/L2)
  unsigned short* F    = (unsigned short*)alloc(NE * 2);             // f bf16 (reused)
  unsigned short* R    = (unsigned short*)alloc(NE * 2);             // r bf16 (layer 1)
  unsigned short* h1b  = (unsigned short*)alloc(NE * 2);             // h1 row-major bf16
  unsigned short* h1sw = (unsigned short*)alloc(NE * 2);             // h1 swizzled bf16
  float* P   = (float*)alloc((size_t)NCHUNK * NCH * 4);
  float* S   = (float*)alloc((size_t)NCHUNK * NCH * 4);
  float* C0  = (float*)alloc((size_t)NCHUNK * NCH * 4);
  float* r2  = (float*)alloc((size_t)NCH * 4);

  dim3 blk256(256);
  // 1. x -> swizzled bf16
  cast_swizzle_f32<<<dim3(M_TOT / 128, 32), blk256, 0, stream>>>(x, xsw, 1024);
  // 2. weights: transpose+cast then swizzle
  transpose_cast<<<dim3(96, 32), dim3(32, 8), 0, stream>>>(W0, W0t, 1024, 3072);
  transpose_cast<<<dim3(96, 32), dim3(32, 8), 0, stream>>>(W1, W1t, 1024, 3072);
  swizzle_bf16<<<dim3(24, 32), blk256, 0, stream>>>(W0t, W0sw, 1024);
  swizzle_bf16<<<dim3(24, 32), blk256, 0, stream>>>(W1t, W1sw, 1024);
  // 3. layer-1 GEMM (N=3072), fused bias+sigmoid split-store
  gemm_sw_fused<<<dim3(24, 256), blk256, 0, stream>>>(xsw, W0sw, Xt, F, R, b0, 1024);
  // 4. blocked scan layer 1
  scan_pass1<<<dim3(NCH / 256, NCHUNK), blk256, 0, stream>>>(Xt, F, P, S);
  combine_c0<<<dim3(NCH / 256), blk256, 0, stream>>>(P, S, C0);
  scan1_pass2<<<dim3(NCH / 256, NCHUNK), blk256, 0, stream>>>(Xt, F, R, x, C0, h1b);
  // 5. h1 -> swizzled
  swizzle_bf16<<<dim3(M_TOT / 128, 32), blk256, 0, stream>>>(h1b, h1sw, 1024);
  // 6. layer-2 GEMM (N=2048: x_tilde + f only)
  gemm_sw_fused<<<dim3(16, 256), blk256, 0, stream>>>(h1sw, W1sw, Xt, F, R, b1, 1024);
  // 7. r2 at last timestep
  r2_kernel<<<dim3(16), dim3(1024), 0, stream>>>(h1b, W1, b1, r2);
  // 8. blocked scan layer 2 (final c only) + output
  scan_pass1<<<dim3(NCH / 256, NCHUNK), blk256, 0, stream>>>(Xt, F, P, S);
  combine_final<<<dim3(NCH / 256), blk256, 0, stream>>>(P, S, r2, h1b, out);
}

// Round 3
// 1035.678 us; speedup vs baseline: 1.0588x; 1.0358x over previous
//
#include <hip/hip_runtime.h>

#define SEQ    2048
#define BATCH  16
#define HID    1024
#define M_TOT  (SEQ*BATCH)      // 32768 rows
#define NCH    (BATCH*HID)      // 16384 scan channels
#define NCHUNK 32
#define TCHUNK (SEQ/NCHUNK)     // 64 timesteps per chunk

typedef __attribute__((ext_vector_type(8))) short          short8;
typedef __attribute__((ext_vector_type(8))) unsigned short ushort8_t;
typedef __attribute__((ext_vector_type(4))) float          floatx4;

__device__ __forceinline__ unsigned short f32_to_bf16(float f) {
  unsigned int u = __float_as_uint(f);
  u += 0x7FFFu + ((u >> 16) & 1u);           // round-to-nearest-even
  return (unsigned short)(u >> 16);
}
__device__ __forceinline__ float bf16_to_f32(unsigned short h) {
  return __uint_as_float(((unsigned int)h) << 16);
}
__device__ __forceinline__ float sigmoidf_(float x) {
  return 1.f / (1.f + __expf(-x));
}

#define LDS_DMA16(gp, lp) \
  __builtin_amdgcn_global_load_lds((const __attribute__((address_space(1))) void*)(gp), \
                                   (__attribute__((address_space(3))) void*)(lp), 16, 0, 0)

// ============================================================================
// Swizzled operand layout ("LDS image"):
//   (R rows, K cols) bf16 -> blocks of 128 rows x 32 k = 4096 ushorts.
//   block = (row>>7)*(K/32) + (k>>5).  Within a block, for (r=row&127, kk=k&31):
//     unit = (r>>4)*64 + ((kk>>3)<<4) + (r&15);  ushort off = unit*8 + (kk&7)
//   GEMM stages 1KB chunks contiguously; lane l ds_read_b128's chunk*1024+l*16.
// ============================================================================

// ---------------- x (fp32 row-major) -> swizzled bf16 -----------------------
__global__ void cast_swizzle_f32(const float* __restrict__ src, unsigned short* __restrict__ dst,
                                 int K) {
  __shared__ unsigned short tile[4096];
  const int mt = blockIdx.x, kt = blockIdx.y;
  const int t = threadIdx.x;
  const int r = t >> 1, kh = (t & 1) * 16;
  const float* sp = src + (size_t)(mt * 128 + r) * K + kt * 32 + kh;
  float4 v0 = *(const float4*)(sp + 0);
  float4 v1 = *(const float4*)(sp + 4);
  float4 v2 = *(const float4*)(sp + 8);
  float4 v3 = *(const float4*)(sp + 12);
  ushort8_t u0, u1;
  u0[0]=f32_to_bf16(v0.x); u0[1]=f32_to_bf16(v0.y); u0[2]=f32_to_bf16(v0.z); u0[3]=f32_to_bf16(v0.w);
  u0[4]=f32_to_bf16(v1.x); u0[5]=f32_to_bf16(v1.y); u0[6]=f32_to_bf16(v1.z); u0[7]=f32_to_bf16(v1.w);
  u1[0]=f32_to_bf16(v2.x); u1[1]=f32_to_bf16(v2.y); u1[2]=f32_to_bf16(v2.z); u1[3]=f32_to_bf16(v2.w);
  u1[4]=f32_to_bf16(v3.x); u1[5]=f32_to_bf16(v3.y); u1[6]=f32_to_bf16(v3.z); u1[7]=f32_to_bf16(v3.w);
  const int c = r >> 4, lr = r & 15, q0 = kh >> 3;
  const int unit0 = c * 64 + (q0 << 4) + lr;
  *(ushort8_t*)&tile[unit0 * 8]        = u0;
  *(ushort8_t*)&tile[(unit0 + 16) * 8] = u1;
  __syncthreads();
  const size_t base = ((size_t)mt * (K >> 5) + kt) * 4096;
  *(ushort8_t*)&dst[base + t * 16]     = *(const ushort8_t*)&tile[t * 16];
  *(ushort8_t*)&dst[base + t * 16 + 8] = *(const ushort8_t*)&tile[t * 16 + 8];
}

// ----- W (1024 x 3072) fp32 -> W^T swizzled bf16 (rows=n, K=1024), one pass --
__global__ void w_prep(const float* __restrict__ W, unsigned short* __restrict__ Wsw) {
  __shared__ unsigned short tile[4096];
  const int nt = blockIdx.x, kt = blockIdx.y;
  const int t = threadIdx.x;
  const int kk = t >> 3, n0 = (t & 7) * 16;
  const float* sp = W + (size_t)(kt * 32 + kk) * 3072 + nt * 128 + n0;
  float v[16];
#pragma unroll
  for (int i = 0; i < 16; i += 4) {
    float4 f = *(const float4*)(sp + i);
    v[i] = f.x; v[i+1] = f.y; v[i+2] = f.z; v[i+3] = f.w;
  }
  const int cbase = (n0 >> 4) * 64 + ((kk >> 3) << 4);
#pragma unroll
  for (int j = 0; j < 16; j++)
    tile[(cbase + j) * 8 + (kk & 7)] = f32_to_bf16(v[j]);
  __syncthreads();
  const size_t base = ((size_t)nt * 32 + kt) * 4096;
  *(ushort8_t*)&Wsw[base + t * 16]     = *(const ushort8_t*)&tile[t * 16];
  *(ushort8_t*)&Wsw[base + t * 16 + 8] = *(const ushort8_t*)&tile[t * 16 + 8];
}

// ---------------------------------------------------------------- MFMA GEMM
// A: swizzled (M,1024).  B: swizzled (N,1024).  128x128x32 tiles, 4 waves.
// 1-D grid with XCD-locality swizzle: xcd=id&7 owns bm slab [xcd*32, +32),
// bn fastest within slab -> A-tile stays hot in local L2 across NBN visits.
// Region (block-uniform): bn<8 -> Xt; 8<=bn<16 -> F; bn>=16 -> R.
__global__ __launch_bounds__(256) void gemm_sw_fused(
    const unsigned short* __restrict__ A, const unsigned short* __restrict__ B,
    unsigned short* __restrict__ Xt, unsigned short* __restrict__ Fo, unsigned short* __restrict__ Ro,
    const float* __restrict__ bias, int NBN)
{
  __shared__ __align__(16) unsigned short As[4096];
  __shared__ __align__(16) unsigned short Bs[4096];
  const int tid = threadIdx.x;
  const int wave = tid >> 6, lane = tid & 63;
  const int id = blockIdx.x;
  const int xcd = id & 7, slot = id >> 3;
  const int bml = slot / NBN;
  const int bn  = slot - bml * NBN;
  const int bm  = xcd * 32 + bml;
  const int wm = wave >> 1, wn = wave & 1;
  const int KT = 32;                     // K = 1024

  const unsigned short* gA = A + (size_t)bm * KT * 4096 + wave * 1024 + lane * 8;
  const unsigned short* gB = B + (size_t)bn * KT * 4096 + wave * 1024 + lane * 8;
  unsigned short* lA = As + wave * 1024;
  unsigned short* lB = Bs + wave * 1024;

  floatx4 acc[4][4];
#pragma unroll
  for (int i = 0; i < 4; i++)
#pragma unroll
    for (int j = 0; j < 4; j++)
#pragma unroll
      for (int r = 0; r < 4; r++) acc[i][j][r] = 0.f;

  const int ra = wm * 2048 + lane * 8;
  const int rb = wn * 2048 + lane * 8;

  for (int kt = 0; kt < KT; ++kt) {
    __syncthreads();
    LDS_DMA16(gA,       lA);
    LDS_DMA16(gA + 512, lA + 512);
    LDS_DMA16(gB,       lB);
    LDS_DMA16(gB + 512, lB + 512);
    gA += 4096; gB += 4096;
    __syncthreads();
    short8 a[4], b[4];
#pragma unroll
    for (int i = 0; i < 4; i++) a[i] = *(const short8*)(As + ra + i * 512);
#pragma unroll
    for (int j = 0; j < 4; j++) b[j] = *(const short8*)(Bs + rb + j * 512);
#pragma unroll
    for (int i = 0; i < 4; i++)
#pragma unroll
      for (int j = 0; j < 4; j++)
        acc[i][j] = __builtin_amdgcn_mfma_f32_16x16x32_bf16(a[i], b[j], acc[i][j], 0, 0, 0);
  }

  // epilogue: C/D layout col=lane&15, row=(lane>>4)*4+reg  [m89/m91-verified]
  const int region = bn >> 3;
  const int colb = (bn & 7) * 128 + wn * 64 + (lane & 15);
  const int row0 = bm * 128 + wm * 64 + ((lane >> 4) << 2);
  if (region == 0) {
#pragma unroll
    for (int i = 0; i < 4; i++)
#pragma unroll
      for (int j = 0; j < 4; j++)
#pragma unroll
        for (int rg = 0; rg < 4; rg++)
          Xt[(size_t)(row0 + i * 16 + rg) * 1024 + colb + j * 16] = f32_to_bf16(acc[i][j][rg]);
  } else {
    unsigned short* O = (region == 1) ? Fo : Ro;
    const float* bp = bias + (region - 1) * 1024;
#pragma unroll
    for (int j = 0; j < 4; j++) {
      float bb = bp[colb + j * 16];
#pragma unroll
      for (int i = 0; i < 4; i++)
#pragma unroll
        for (int rg = 0; rg < 4; rg++) {
          float s = sigmoidf_(acc[i][j][rg] + bb);
          O[(size_t)(row0 + i * 16 + rg) * 1024 + colb + j * 16] = f32_to_bf16(s);
        }
    }
  }
}

// -------------------------------------------------- blocked scan pass 1
__global__ void scan_pass1(const unsigned short* __restrict__ Xt, const unsigned short* __restrict__ F,
                           float* __restrict__ P, float* __restrict__ S) {
  int ch = blockIdx.x * blockDim.x + threadIdx.x;
  int chunk = blockIdx.y;
  size_t idx = (size_t)chunk * TCHUNK * NCH + ch;
  float p = 1.f, s = 0.f;
  for (int t = 0; t < TCHUNK; ++t) {
    float f  = bf16_to_f32(F[idx]);
    float xt = bf16_to_f32(Xt[idx]);
    s = f * s + (1.f - f) * xt;
    p *= f;
    idx += NCH;
  }
  P[(size_t)chunk * NCH + ch] = p;
  S[(size_t)chunk * NCH + ch] = s;
}

// -------------------------------------------------- serial combine -> carries
__global__ void combine_c0(const float* __restrict__ P, const float* __restrict__ S,
                           float* __restrict__ C0) {
  int ch = blockIdx.x * blockDim.x + threadIdx.x;
  float c = 0.f;
  for (int k = 0; k < NCHUNK; ++k) {
    C0[(size_t)k * NCH + ch] = c;
    c = P[(size_t)k * NCH + ch] * c + S[(size_t)k * NCH + ch];
  }
}

// ------- pass 2 (layer 1): h1 = r*c + (1-r)*x, written DIRECTLY swizzled ----
// swizzled offset for (row m = 16t+b, k = h):
//   ((t>>3)*32 + (h>>5))*4096 + ((t&7)*64 + ((h>>3)&3)*16 + b)*8 + (h&7)
__global__ void scan1_pass2(const unsigned short* __restrict__ Xt, const unsigned short* __restrict__ F,
                            const unsigned short* __restrict__ R, const unsigned short* __restrict__ xsw,
                            const float* __restrict__ C0, unsigned short* __restrict__ h1sw,
                            unsigned short* __restrict__ h1last) {
  int ch = blockIdx.x * blockDim.x + threadIdx.x;
  int chunk = blockIdx.y;
  const int b = ch >> 10, h = ch & 1023;
  float c = C0[(size_t)chunk * NCH + ch];
  size_t idx = (size_t)chunk * TCHUNK * NCH + ch;
  const int hblk = h >> 5;
  const int lsub = ((h >> 3) & 3) * 16 + b;
  const int h7 = h & 7;
  unsigned short last = 0;
  for (int tt = 0; tt < TCHUNK; ++tt) {
    const int t = chunk * TCHUNK + tt;
    float f  = bf16_to_f32(F[idx]);
    float xt = bf16_to_f32(Xt[idx]);
    c = f * c + (1.f - f) * xt;
    float r  = bf16_to_f32(R[idx]);
    size_t soff = ((size_t)(t >> 3) * 32 + hblk) * 4096
                + (size_t)(((t & 7) * 64 + lsub) * 8 + h7);
    float xv = bf16_to_f32(xsw[soff]);
    unsigned short hv = f32_to_bf16(r * c + (1.f - r) * xv);
    h1sw[soff] = hv;
    last = hv;
    idx += NCH;
  }
  if (chunk == NCHUNK - 1) h1last[ch] = last;
}

// ------- r2 at last timestep: (16x1024) @ W1[:,2048:3072] fp32, 64 blocks ---
__global__ void r2_kernel(const unsigned short* __restrict__ h1last, const float* __restrict__ W1,
                          const float* __restrict__ b1, float* __restrict__ r2) {
  __shared__ float xrow[1024];
  const int b = blockIdx.x, nq = blockIdx.y, tid = threadIdx.x;
  for (int i = tid; i < 1024; i += 256) xrow[i] = bf16_to_f32(h1last[b * 1024 + i]);
  __syncthreads();
  const int n = nq * 256 + tid;
  float acc = b1[1024 + n];
  for (int d = 0; d < 1024; ++d)
    acc += xrow[d] * W1[(size_t)d * 3072 + 2048 + n];
  r2[b * 1024 + n] = sigmoidf_(acc);
}

// -------------------------------------------------- layer-2 combine + output
__global__ void combine_final(const float* __restrict__ P, const float* __restrict__ S,
                              const float* __restrict__ r2, const unsigned short* __restrict__ h1last,
                              float* __restrict__ out) {
  int ch = blockIdx.x * blockDim.x + threadIdx.x;
  float c = 0.f;
  for (int k = 0; k < NCHUNK; ++k)
    c = P[(size_t)k * NCH + ch] * c + S[(size_t)k * NCH + ch];
  float r = r2[ch];
  float x = bf16_to_f32(h1last[ch]);
  out[ch] = r * c + (1.f - r) * x;
}

extern "C" void kernel_launch(void* const* d_in, const int* in_sizes, int n_in,
                              void* d_out, int out_size, void* d_ws, size_t ws_size,
                              hipStream_t stream) {
  const float* x  = (const float*)d_in[0];
  const float* W0 = (const float*)d_in[1];
  const float* b0 = (const float*)d_in[2];
  const float* W1 = (const float*)d_in[3];
  const float* b1 = (const float*)d_in[4];
  float* out = (float*)d_out;

  char* ws = (char*)d_ws;
  auto alloc = [&](size_t bytes) {
    char* p = ws; ws += (bytes + 255) & ~(size_t)255; return p;
  };
  const size_t NE = (size_t)M_TOT * HID;
  unsigned short* xsw   = (unsigned short*)alloc(NE * 2);            // x swizzled bf16
  unsigned short* W0sw  = (unsigned short*)alloc((size_t)3072 * 1024 * 2);
  unsigned short* W1sw  = (unsigned short*)alloc((size_t)3072 * 1024 * 2);
  unsigned short* Xt    = (unsigned short*)alloc(NE * 2);            // x_tilde bf16 row-major
  unsigned short* F     = (unsigned short*)alloc(NE * 2);            // f bf16 row-major
  unsigned short* R     = (unsigned short*)alloc(NE * 2);            // r bf16 (layer 1)
  unsigned short* h1sw  = (unsigned short*)alloc(NE * 2);            // h1 swizzled bf16
  unsigned short* h1last= (unsigned short*)alloc((size_t)NCH * 2);   // h1 at t=2047
  float* P   = (float*)alloc((size_t)NCHUNK * NCH * 4);
  float* S   = (float*)alloc((size_t)NCHUNK * NCH * 4);
  float* C0  = (float*)alloc((size_t)NCHUNK * NCH * 4);
  float* r2  = (float*)alloc((size_t)NCH * 4);

  dim3 blk256(256);
  // 1. x -> swizzled bf16
  cast_swizzle_f32<<<dim3(M_TOT / 128, 32), blk256, 0, stream>>>(x, xsw, 1024);
  // 2. weights -> W^T swizzled bf16 (single pass each)
  w_prep<<<dim3(24, 32), blk256, 0, stream>>>(W0, W0sw);
  w_prep<<<dim3(24, 32), blk256, 0, stream>>>(W1, W1sw);
  // 3. layer-1 GEMM (N=3072), XCD-swizzled 1-D grid
  gemm_sw_fused<<<dim3(24 * 256), blk256, 0, stream>>>(xsw, W0sw, Xt, F, R, b0, 24);
  // 4. blocked scan layer 1
  scan_pass1<<<dim3(NCH / 256, NCHUNK), blk256, 0, stream>>>(Xt, F, P, S);
  combine_c0<<<dim3(NCH / 256), blk256, 0, stream>>>(P, S, C0);
  scan1_pass2<<<dim3(NCH / 256, NCHUNK), blk256, 0, stream>>>(Xt, F, R, xsw, C0, h1sw, h1last);
  // 5. layer-2 GEMM (N=2048: x_tilde + f only)
  gemm_sw_fused<<<dim3(16 * 256), blk256, 0, stream>>>(h1sw, W1sw, Xt, F, R, b1, 16);
  // 6. r2 at last timestep
  r2_kernel<<<dim3(16, 4), blk256, 0, stream>>>(h1last, W1, b1, r2);
  // 7. blocked scan layer 2 (final c only) + output
  scan_pass1<<<dim3(NCH / 256, NCHUNK), blk256, 0, stream>>>(Xt, F, P, S);
  combine_final<<<dim3(NCH / 256), blk256, 0, stream>>>(P, S, r2, h1last, out);
}

// Round 4
// 861.417 us; speedup vs baseline: 1.2730x; 1.2023x over previous
//
#include <hip/hip_runtime.h>

#define SEQ    2048
#define BATCH  16
#define HID    1024
#define M_TOT  (SEQ*BATCH)      // 32768 rows
#define NCH    (BATCH*HID)      // 16384 scan channels
#define NCHUNK 32
#define TCHUNK (SEQ/NCHUNK)     // 64 timesteps per chunk

typedef __attribute__((ext_vector_type(8))) short          short8;
typedef __attribute__((ext_vector_type(8))) unsigned short ushort8_t;
typedef __attribute__((ext_vector_type(4))) float          floatx4;

__device__ __forceinline__ unsigned short f32_to_bf16(float f) {
  unsigned int u = __float_as_uint(f);
  u += 0x7FFFu + ((u >> 16) & 1u);           // round-to-nearest-even
  return (unsigned short)(u >> 16);
}
__device__ __forceinline__ float bf16_to_f32(unsigned short h) {
  return __uint_as_float(((unsigned int)h) << 16);
}
__device__ __forceinline__ float sigmoidf_(float x) {
  return 1.f / (1.f + __expf(-x));
}

#define LDS_DMA16(gp, lp) \
  __builtin_amdgcn_global_load_lds((const __attribute__((address_space(1))) void*)(gp), \
                                   (__attribute__((address_space(3))) void*)(lp), 16, 0, 0)

// ============================================================================
// Swizzled operand layout ("LDS image"):
//   (R rows, K cols) bf16 -> blocks of 128 rows x 32 k = 4096 ushorts.
//   block = (row>>7)*(K/32) + (k>>5).  Within a block, for (r=row&127, kk=k&31):
//     unit = (r>>4)*64 + ((kk>>3)<<4) + (r&15);  ushort off = unit*8 + (kk&7)
//   GEMM stages 1KB chunks contiguously; lane l ds_read_b128's chunk*1024+l*16.
// ============================================================================

// ---------------- x (fp32 row-major) -> swizzled bf16 -----------------------
__global__ void cast_swizzle_f32(const float* __restrict__ src, unsigned short* __restrict__ dst,
                                 int K) {
  __shared__ unsigned short tile[4096];
  const int mt = blockIdx.x, kt = blockIdx.y;
  const int t = threadIdx.x;
  const int r = t >> 1, kh = (t & 1) * 16;
  const float* sp = src + (size_t)(mt * 128 + r) * K + kt * 32 + kh;
  float4 v0 = *(const float4*)(sp + 0);
  float4 v1 = *(const float4*)(sp + 4);
  float4 v2 = *(const float4*)(sp + 8);
  float4 v3 = *(const float4*)(sp + 12);
  ushort8_t u0, u1;
  u0[0]=f32_to_bf16(v0.x); u0[1]=f32_to_bf16(v0.y); u0[2]=f32_to_bf16(v0.z); u0[3]=f32_to_bf16(v0.w);
  u0[4]=f32_to_bf16(v1.x); u0[5]=f32_to_bf16(v1.y); u0[6]=f32_to_bf16(v1.z); u0[7]=f32_to_bf16(v1.w);
  u1[0]=f32_to_bf16(v2.x); u1[1]=f32_to_bf16(v2.y); u1[2]=f32_to_bf16(v2.z); u1[3]=f32_to_bf16(v2.w);
  u1[4]=f32_to_bf16(v3.x); u1[5]=f32_to_bf16(v3.y); u1[6]=f32_to_bf16(v3.z); u1[7]=f32_to_bf16(v3.w);
  const int c = r >> 4, lr = r & 15, q0 = kh >> 3;
  const int unit0 = c * 64 + (q0 << 4) + lr;
  *(ushort8_t*)&tile[unit0 * 8]        = u0;
  *(ushort8_t*)&tile[(unit0 + 16) * 8] = u1;
  __syncthreads();
  const size_t base = ((size_t)mt * (K >> 5) + kt) * 4096;
  *(ushort8_t*)&dst[base + t * 16]     = *(const ushort8_t*)&tile[t * 16];
  *(ushort8_t*)&dst[base + t * 16 + 8] = *(const ushort8_t*)&tile[t * 16 + 8];
}

// ---------------- row-major bf16 -> swizzled bf16 (both sides coalesced) ----
__global__ void swizzle_bf16(const unsigned short* __restrict__ src, unsigned short* __restrict__ dst,
                             int K) {
  __shared__ unsigned short tile[4096];
  const int mt = blockIdx.x, kt = blockIdx.y;
  const int t = threadIdx.x;
  const int r = t >> 1, kh = (t & 1) * 16;
  const unsigned short* sp = src + (size_t)(mt * 128 + r) * K + kt * 32 + kh;
  ushort8_t u0 = *(const ushort8_t*)(sp + 0);
  ushort8_t u1 = *(const ushort8_t*)(sp + 8);
  const int c = r >> 4, lr = r & 15, q0 = kh >> 3;
  const int unit0 = c * 64 + (q0 << 4) + lr;
  *(ushort8_t*)&tile[unit0 * 8]        = u0;
  *(ushort8_t*)&tile[(unit0 + 16) * 8] = u1;
  __syncthreads();
  const size_t base = ((size_t)mt * (K >> 5) + kt) * 4096;
  *(ushort8_t*)&dst[base + t * 16]     = *(const ushort8_t*)&tile[t * 16];
  *(ushort8_t*)&dst[base + t * 16 + 8] = *(const ushort8_t*)&tile[t * 16 + 8];
}

// ----- W (1024 x 3072) fp32 -> W^T swizzled bf16 (rows=n, K=1024), one pass --
__global__ void w_prep(const float* __restrict__ W, unsigned short* __restrict__ Wsw) {
  __shared__ unsigned short tile[4096];
  const int nt = blockIdx.x, kt = blockIdx.y;
  const int t = threadIdx.x;
  const int kk = t >> 3, n0 = (t & 7) * 16;
  const float* sp = W + (size_t)(kt * 32 + kk) * 3072 + nt * 128 + n0;
  float v[16];
#pragma unroll
  for (int i = 0; i < 16; i += 4) {
    float4 f = *(const float4*)(sp + i);
    v[i] = f.x; v[i+1] = f.y; v[i+2] = f.z; v[i+3] = f.w;
  }
  const int cbase = (n0 >> 4) * 64 + ((kk >> 3) << 4);
#pragma unroll
  for (int j = 0; j < 16; j++)
    tile[(cbase + j) * 8 + (kk & 7)] = f32_to_bf16(v[j]);
  __syncthreads();
  const size_t base = ((size_t)nt * 32 + kt) * 4096;
  *(ushort8_t*)&Wsw[base + t * 16]     = *(const ushort8_t*)&tile[t * 16];
  *(ushort8_t*)&Wsw[base + t * 16 + 8] = *(const ushort8_t*)&tile[t * 16 + 8];
}

// ---------------------------------------------------------------- MFMA GEMM
// A: swizzled (M,1024).  B: swizzled (N,1024).  128x128x32 tiles, 4 waves.
// Double-buffered LDS K-loop, ONE barrier per tile: prefetch tile k+1 after
// the barrier, drain at the next barrier (a full compute phase covers it).
// XCD-locality: xcd=id&7 owns bm slab, bn fastest.
// Region (block-uniform): bn<8 -> Xt; 8<=bn<16 -> F; bn>=16 -> R.
__global__ __launch_bounds__(256, 4) void gemm_sw_fused(
    const unsigned short* __restrict__ A, const unsigned short* __restrict__ B,
    unsigned short* __restrict__ Xt, unsigned short* __restrict__ Fo, unsigned short* __restrict__ Ro,
    const float* __restrict__ bias, int NBN)
{
  __shared__ __align__(16) unsigned short As[2][4096];
  __shared__ __align__(16) unsigned short Bs[2][4096];
  const int tid = threadIdx.x;
  const int wave = tid >> 6, lane = tid & 63;
  const int id = blockIdx.x;
  const int xcd = id & 7, slot = id >> 3;
  const int bml = slot / NBN;
  const int bn  = slot - bml * NBN;
  const int bm  = xcd * 32 + bml;
  const int wm = wave >> 1, wn = wave & 1;

  const int so = wave * 1024 + lane * 8;          // staging offset (ushorts)
  const unsigned short* gA = A + (size_t)bm * 32 * 4096 + so;
  const unsigned short* gB = B + (size_t)bn * 32 * 4096 + so;
  const int l0 = wave * 1024;                      // wave-uniform LDS chunk base

  floatx4 acc[4][4];
#pragma unroll
  for (int i = 0; i < 4; i++)
#pragma unroll
    for (int j = 0; j < 4; j++)
#pragma unroll
      for (int r = 0; r < 4; r++) acc[i][j][r] = 0.f;

  const int ra = wm * 2048 + lane * 8;
  const int rb = wn * 2048 + lane * 8;

  auto stage = [&](int buf) {
    LDS_DMA16(gA,       As[buf] + l0);
    LDS_DMA16(gA + 512, As[buf] + l0 + 512);
    LDS_DMA16(gB,       Bs[buf] + l0);
    LDS_DMA16(gB + 512, Bs[buf] + l0 + 512);
    gA += 4096; gB += 4096;
  };
  auto compute = [&](int buf) {
    short8 a[4], b[4];
#pragma unroll
    for (int i = 0; i < 4; i++) a[i] = *(const short8*)(As[buf] + ra + i * 512);
#pragma unroll
    for (int j = 0; j < 4; j++) b[j] = *(const short8*)(Bs[buf] + rb + j * 512);
#pragma unroll
    for (int i = 0; i < 4; i++)
#pragma unroll
      for (int j = 0; j < 4; j++)
        acc[i][j] = __builtin_amdgcn_mfma_f32_16x16x32_bf16(a[i], b[j], acc[i][j], 0, 0, 0);
  };

  stage(0);                                  // prologue: tile 0 in flight
#pragma unroll 1
  for (int kt = 0; kt < 32; kt += 2) {
    __syncthreads();                         // tile kt resident in buf0; buf1 reads done
    stage(1);                                // prefetch tile kt+1 (overlaps compute)
    compute(0);
    __syncthreads();                         // tile kt+1 resident in buf1; buf0 reads done
    if (kt + 2 < 32) stage(0);               // prefetch tile kt+2
    compute(1);
  }

  // epilogue: C/D layout col=lane&15, row=(lane>>4)*4+reg  [m89/m91-verified]
  const int region = bn >> 3;
  const int colb = (bn & 7) * 128 + wn * 64 + (lane & 15);
  const int row0 = bm * 128 + wm * 64 + ((lane >> 4) << 2);
  if (region == 0) {
#pragma unroll
    for (int i = 0; i < 4; i++)
#pragma unroll
      for (int j = 0; j < 4; j++)
#pragma unroll
        for (int rg = 0; rg < 4; rg++)
          Xt[(size_t)(row0 + i * 16 + rg) * 1024 + colb + j * 16] = f32_to_bf16(acc[i][j][rg]);
  } else {
    unsigned short* O = (region == 1) ? Fo : Ro;
    const float* bp = bias + (region - 1) * 1024;
#pragma unroll
    for (int j = 0; j < 4; j++) {
      float bb = bp[colb + j * 16];
#pragma unroll
      for (int i = 0; i < 4; i++)
#pragma unroll
        for (int rg = 0; rg < 4; rg++) {
          float s = sigmoidf_(acc[i][j][rg] + bb);
          O[(size_t)(row0 + i * 16 + rg) * 1024 + colb + j * 16] = f32_to_bf16(s);
        }
    }
  }
}

// -------------------------------------------------- blocked scan pass 1
__global__ void scan_pass1(const unsigned short* __restrict__ Xt, const unsigned short* __restrict__ F,
                           float* __restrict__ P, float* __restrict__ S) {
  int ch = blockIdx.x * blockDim.x + threadIdx.x;
  int chunk = blockIdx.y;
  size_t idx = (size_t)chunk * TCHUNK * NCH + ch;
  float p = 1.f, s = 0.f;
  for (int t = 0; t < TCHUNK; ++t) {
    float f  = bf16_to_f32(F[idx]);
    float xt = bf16_to_f32(Xt[idx]);
    s = f * s + (1.f - f) * xt;
    p *= f;
    idx += NCH;
  }
  P[(size_t)chunk * NCH + ch] = p;
  S[(size_t)chunk * NCH + ch] = s;
}

// -------------------------------------------------- serial combine -> carries
__global__ void combine_c0(const float* __restrict__ P, const float* __restrict__ S,
                           float* __restrict__ C0) {
  int ch = blockIdx.x * blockDim.x + threadIdx.x;
  float c = 0.f;
  for (int k = 0; k < NCHUNK; ++k) {
    C0[(size_t)k * NCH + ch] = c;
    c = P[(size_t)k * NCH + ch] * c + S[(size_t)k * NCH + ch];
  }
}

// -------- pass 2 (layer 1): h1 = r*c + (1-r)*x, row-major bf16 (coalesced) --
__global__ void scan1_pass2(const unsigned short* __restrict__ Xt, const unsigned short* __restrict__ F,
                            const unsigned short* __restrict__ R, const float* __restrict__ x,
                            const float* __restrict__ C0, unsigned short* __restrict__ h1b) {
  int ch = blockIdx.x * blockDim.x + threadIdx.x;
  int chunk = blockIdx.y;
  float c = C0[(size_t)chunk * NCH + ch];
  size_t idx = (size_t)chunk * TCHUNK * NCH + ch;
  for (int t = 0; t < TCHUNK; ++t) {
    float f  = bf16_to_f32(F[idx]);
    float xt = bf16_to_f32(Xt[idx]);
    c = f * c + (1.f - f) * xt;
    float r  = bf16_to_f32(R[idx]);
    float xv = x[idx];
    h1b[idx] = f32_to_bf16(r * c + (1.f - r) * xv);
    idx += NCH;
  }
}

// ------- r2 at last timestep: (16x1024) @ W1[:,2048:3072] fp32, 64 blocks ---
__global__ void r2_kernel(const unsigned short* __restrict__ h1b, const float* __restrict__ W1,
                          const float* __restrict__ b1, float* __restrict__ r2) {
  __shared__ float xrow[1024];
  const int b = blockIdx.x, nq = blockIdx.y, tid = threadIdx.x;
  for (int i = tid; i < 1024; i += 256)
    xrow[i] = bf16_to_f32(h1b[(size_t)(2047 * 16 + b) * 1024 + i]);
  __syncthreads();
  const int n = nq * 256 + tid;
  float acc = b1[1024 + n];
  for (int d = 0; d < 1024; ++d)
    acc += xrow[d] * W1[(size_t)d * 3072 + 2048 + n];
  r2[b * 1024 + n] = sigmoidf_(acc);
}

// -------------------------------------------------- layer-2 combine + output
__global__ void combine_final(const float* __restrict__ P, const float* __restrict__ S,
                              const float* __restrict__ r2, const unsigned short* __restrict__ h1b,
                              float* __restrict__ out) {
  int ch = blockIdx.x * blockDim.x + threadIdx.x;
  float c = 0.f;
  for (int k = 0; k < NCHUNK; ++k)
    c = P[(size_t)k * NCH + ch] * c + S[(size_t)k * NCH + ch];
  float r = r2[ch];
  float x = bf16_to_f32(h1b[(size_t)2047 * NCH + ch]);
  out[ch] = r * c + (1.f - r) * x;
}

extern "C" void kernel_launch(void* const* d_in, const int* in_sizes, int n_in,
                              void* d_out, int out_size, void* d_ws, size_t ws_size,
                              hipStream_t stream) {
  const float* x  = (const float*)d_in[0];
  const float* W0 = (const float*)d_in[1];
  const float* b0 = (const float*)d_in[2];
  const float* W1 = (const float*)d_in[3];
  const float* b1 = (const float*)d_in[4];
  float* out = (float*)d_out;

  char* ws = (char*)d_ws;
  auto alloc = [&](size_t bytes) {
    char* p = ws; ws += (bytes + 255) & ~(size_t)255; return p;
  };
  const size_t NE = (size_t)M_TOT * HID;
  unsigned short* xsw   = (unsigned short*)alloc(NE * 2);            // x swizzled bf16
  unsigned short* W0sw  = (unsigned short*)alloc((size_t)3072 * 1024 * 2);
  unsigned short* W1sw  = (unsigned short*)alloc((size_t)3072 * 1024 * 2);
  unsigned short* Xt    = (unsigned short*)alloc(NE * 2);            // x_tilde bf16 row-major
  unsigned short* F     = (unsigned short*)alloc(NE * 2);            // f bf16 row-major
  unsigned short* R     = (unsigned short*)alloc(NE * 2);            // r bf16 (layer 1)
  unsigned short* h1b   = (unsigned short*)alloc(NE * 2);            // h1 row-major bf16
  unsigned short* h1sw  = (unsigned short*)alloc(NE * 2);            // h1 swizzled bf16
  float* P   = (float*)alloc((size_t)NCHUNK * NCH * 4);
  float* S   = (float*)alloc((size_t)NCHUNK * NCH * 4);
  float* C0  = (float*)alloc((size_t)NCHUNK * NCH * 4);
  float* r2  = (float*)alloc((size_t)NCH * 4);

  dim3 blk256(256);
  // 1. x -> swizzled bf16
  cast_swizzle_f32<<<dim3(M_TOT / 128, 32), blk256, 0, stream>>>(x, xsw, 1024);
  // 2. weights -> W^T swizzled bf16 (single pass each)
  w_prep<<<dim3(24, 32), blk256, 0, stream>>>(W0, W0sw);
  w_prep<<<dim3(24, 32), blk256, 0, stream>>>(W1, W1sw);
  // 3. layer-1 GEMM (N=3072), XCD-swizzled 1-D grid, dbuf K-loop
  gemm_sw_fused<<<dim3(24 * 256), blk256, 0, stream>>>(xsw, W0sw, Xt, F, R, b0, 24);
  // 4. blocked scan layer 1
  scan_pass1<<<dim3(NCH / 256, NCHUNK), blk256, 0, stream>>>(Xt, F, P, S);
  combine_c0<<<dim3(NCH / 256), blk256, 0, stream>>>(P, S, C0);
  scan1_pass2<<<dim3(NCH / 256, NCHUNK), blk256, 0, stream>>>(Xt, F, R, x, C0, h1b);
  // 5. h1 -> swizzled (coalesced both sides)
  swizzle_bf16<<<dim3(M_TOT / 128, 32), blk256, 0, stream>>>(h1b, h1sw, 1024);
  // 6. layer-2 GEMM (N=2048: x_tilde + f only)
  gemm_sw_fused<<<dim3(16 * 256), blk256, 0, stream>>>(h1sw, W1sw, Xt, F, R, b1, 16);
  // 7. r2 at last timestep
  r2_kernel<<<dim3(16, 4), blk256, 0, stream>>>(h1b, W1, b1, r2);
  // 8. blocked scan layer 2 (final c only) + output
  scan_pass1<<<dim3(NCH / 256, NCHUNK), blk256, 0, stream>>>(Xt, F, P, S);
  combine_final<<<dim3(NCH / 256), blk256, 0, stream>>>(P, S, r2, h1b, out);
}

// Round 5
// 838.543 us; speedup vs baseline: 1.3078x; 1.0273x over previous
//
#include <hip/hip_runtime.h>

#define SEQ    2048
#define BATCH  16
#define HID    1024
#define M_TOT  (SEQ*BATCH)      // 32768 rows
#define NCH    (BATCH*HID)      // 16384 scan channels
#define NCHUNK 32
#define TCHUNK (SEQ/NCHUNK)     // 64 timesteps per chunk

typedef __attribute__((ext_vector_type(8))) short          short8;
typedef __attribute__((ext_vector_type(8))) unsigned short ushort8_t;
typedef __attribute__((ext_vector_type(4))) float          floatx4;

__device__ __forceinline__ unsigned short f32_to_bf16(float f) {
  unsigned int u = __float_as_uint(f);
  u += 0x7FFFu + ((u >> 16) & 1u);           // round-to-nearest-even
  return (unsigned short)(u >> 16);
}
__device__ __forceinline__ float bf16_to_f32(unsigned short h) {
  return __uint_as_float(((unsigned int)h) << 16);
}
__device__ __forceinline__ float sigmoidf_(float x) {
  return 1.f / (1.f + __expf(-x));
}

#define LDS_DMA16(gp, lp) \
  __builtin_amdgcn_global_load_lds((const __attribute__((address_space(1))) void*)(gp), \
                                   (__attribute__((address_space(3))) void*)(lp), 16, 0, 0)

// ============================================================================
// Swizzled operand layout ("LDS image"):
//   (R rows, K cols) bf16 -> blocks of 128 rows x 32 k = 4096 ushorts.
//   block = (row>>7)*(K/32) + (k>>5).  Within a block, for (r=row&127, kk=k&31):
//     unit = (r>>4)*64 + ((kk>>3)<<4) + (r&15);  ushort off = unit*8 + (kk&7)
//   GEMM stages 1KB chunks contiguously; lane l ds_read_b128's chunk*1024+l*16.
// ============================================================================

// ---------------- x (fp32 row-major) -> swizzled bf16 -----------------------
__global__ void cast_swizzle_f32(const float* __restrict__ src, unsigned short* __restrict__ dst,
                                 int K) {
  __shared__ unsigned short tile[4096];
  const int mt = blockIdx.x, kt = blockIdx.y;
  const int t = threadIdx.x;
  const int r = t >> 1, kh = (t & 1) * 16;
  const float* sp = src + (size_t)(mt * 128 + r) * K + kt * 32 + kh;
  float4 v0 = *(const float4*)(sp + 0);
  float4 v1 = *(const float4*)(sp + 4);
  float4 v2 = *(const float4*)(sp + 8);
  float4 v3 = *(const float4*)(sp + 12);
  ushort8_t u0, u1;
  u0[0]=f32_to_bf16(v0.x); u0[1]=f32_to_bf16(v0.y); u0[2]=f32_to_bf16(v0.z); u0[3]=f32_to_bf16(v0.w);
  u0[4]=f32_to_bf16(v1.x); u0[5]=f32_to_bf16(v1.y); u0[6]=f32_to_bf16(v1.z); u0[7]=f32_to_bf16(v1.w);
  u1[0]=f32_to_bf16(v2.x); u1[1]=f32_to_bf16(v2.y); u1[2]=f32_to_bf16(v2.z); u1[3]=f32_to_bf16(v2.w);
  u1[4]=f32_to_bf16(v3.x); u1[5]=f32_to_bf16(v3.y); u1[6]=f32_to_bf16(v3.z); u1[7]=f32_to_bf16(v3.w);
  const int c = r >> 4, lr = r & 15, q0 = kh >> 3;
  const int unit0 = c * 64 + (q0 << 4) + lr;
  *(ushort8_t*)&tile[unit0 * 8]        = u0;
  *(ushort8_t*)&tile[(unit0 + 16) * 8] = u1;
  __syncthreads();
  const size_t base = ((size_t)mt * (K >> 5) + kt) * 4096;
  *(ushort8_t*)&dst[base + t * 16]     = *(const ushort8_t*)&tile[t * 16];
  *(ushort8_t*)&dst[base + t * 16 + 8] = *(const ushort8_t*)&tile[t * 16 + 8];
}

// ---------------- row-major bf16 -> swizzled bf16 (both sides coalesced) ----
__global__ void swizzle_bf16(const unsigned short* __restrict__ src, unsigned short* __restrict__ dst,
                             int K) {
  __shared__ unsigned short tile[4096];
  const int mt = blockIdx.x, kt = blockIdx.y;
  const int t = threadIdx.x;
  const int r = t >> 1, kh = (t & 1) * 16;
  const unsigned short* sp = src + (size_t)(mt * 128 + r) * K + kt * 32 + kh;
  ushort8_t u0 = *(const ushort8_t*)(sp + 0);
  ushort8_t u1 = *(const ushort8_t*)(sp + 8);
  const int c = r >> 4, lr = r & 15, q0 = kh >> 3;
  const int unit0 = c * 64 + (q0 << 4) + lr;
  *(ushort8_t*)&tile[unit0 * 8]        = u0;
  *(ushort8_t*)&tile[(unit0 + 16) * 8] = u1;
  __syncthreads();
  const size_t base = ((size_t)mt * (K >> 5) + kt) * 4096;
  *(ushort8_t*)&dst[base + t * 16]     = *(const ushort8_t*)&tile[t * 16];
  *(ushort8_t*)&dst[base + t * 16 + 8] = *(const ushort8_t*)&tile[t * 16 + 8];
}

// ----- W (1024 x 3072) fp32 -> W^T swizzled bf16 (rows=n, K=1024), one pass --
__global__ void w_prep(const float* __restrict__ W, unsigned short* __restrict__ Wsw) {
  __shared__ unsigned short tile[4096];
  const int nt = blockIdx.x, kt = blockIdx.y;
  const int t = threadIdx.x;
  const int kk = t >> 3, n0 = (t & 7) * 16;
  const float* sp = W + (size_t)(kt * 32 + kk) * 3072 + nt * 128 + n0;
  float v[16];
#pragma unroll
  for (int i = 0; i < 16; i += 4) {
    float4 f = *(const float4*)(sp + i);
    v[i] = f.x; v[i+1] = f.y; v[i+2] = f.z; v[i+3] = f.w;
  }
  const int cbase = (n0 >> 4) * 64 + ((kk >> 3) << 4);
#pragma unroll
  for (int j = 0; j < 16; j++)
    tile[(cbase + j) * 8 + (kk & 7)] = f32_to_bf16(v[j]);
  __syncthreads();
  const size_t base = ((size_t)nt * 32 + kt) * 4096;
  *(ushort8_t*)&Wsw[base + t * 16]     = *(const ushort8_t*)&tile[t * 16];
  *(ushort8_t*)&Wsw[base + t * 16 + 8] = *(const ushort8_t*)&tile[t * 16 + 8];
}

// ---------------------------------------------------------------- MFMA GEMM
// A: swizzled (M,1024).  B: swizzled (N,1024).  128x128x32 tiles, 4 waves,
// double-buffered LDS K-loop (one barrier per tile).
// XCD-locality + L2 working-set shaping: xcd=id&7 owns bm slab [xcd*32,+32);
// within the slab, blocks are ordered (group of 8 bml) x (bn) x (bml in group)
// so co-resident blocks share 8 A-tiles (2 MB) + ~1 B-tile (256 KB) -> fits
// the 4 MB per-XCD L2 (R4 showed 560 MB FETCH = L2 thrash at 32-tile set).
// Region (block-uniform): bn<8 -> Xt; 8<=bn<16 -> F; bn>=16 -> R.
__global__ __launch_bounds__(256, 4) void gemm_sw_fused(
    const unsigned short* __restrict__ A, const unsigned short* __restrict__ B,
    unsigned short* __restrict__ Xt, unsigned short* __restrict__ Fo, unsigned short* __restrict__ Ro,
    const float* __restrict__ bias, int NBN)
{
  __shared__ __align__(16) unsigned short As[2][4096];
  __shared__ __align__(16) unsigned short Bs[2][4096];
  const int tid = threadIdx.x;
  const int wave = tid >> 6, lane = tid & 63;
  const int id = blockIdx.x;
  const int xcd = id & 7, slot = id >> 3;
  const int NB8 = NBN << 3;                  // blocks per bml-group
  const int g    = slot / NB8;               // bml group (8 tiles = 2 MB of A)
  const int rem  = slot - g * NB8;
  const int bn   = rem >> 3;                 // B-tile sweeps within group
  const int bm   = xcd * 32 + g * 8 + (rem & 7);
  const int wm = wave >> 1, wn = wave & 1;

  const int so = wave * 1024 + lane * 8;          // staging offset (ushorts)
  const unsigned short* gA = A + (size_t)bm * 32 * 4096 + so;
  const unsigned short* gB = B + (size_t)bn * 32 * 4096 + so;
  const int l0 = wave * 1024;                      // wave-uniform LDS chunk base

  floatx4 acc[4][4];
#pragma unroll
  for (int i = 0; i < 4; i++)
#pragma unroll
    for (int j = 0; j < 4; j++)
#pragma unroll
      for (int r = 0; r < 4; r++) acc[i][j][r] = 0.f;

  const int ra = wm * 2048 + lane * 8;
  const int rb = wn * 2048 + lane * 8;

  auto stage = [&](int buf) {
    LDS_DMA16(gA,       As[buf] + l0);
    LDS_DMA16(gA + 512, As[buf] + l0 + 512);
    LDS_DMA16(gB,       Bs[buf] + l0);
    LDS_DMA16(gB + 512, Bs[buf] + l0 + 512);
    gA += 4096; gB += 4096;
  };
  auto compute = [&](int buf) {
    short8 a[4], b[4];
#pragma unroll
    for (int i = 0; i < 4; i++) a[i] = *(const short8*)(As[buf] + ra + i * 512);
#pragma unroll
    for (int j = 0; j < 4; j++) b[j] = *(const short8*)(Bs[buf] + rb + j * 512);
#pragma unroll
    for (int i = 0; i < 4; i++)
#pragma unroll
      for (int j = 0; j < 4; j++)
        acc[i][j] = __builtin_amdgcn_mfma_f32_16x16x32_bf16(a[i], b[j], acc[i][j], 0, 0, 0);
  };

  stage(0);                                  // prologue: tile 0 in flight
#pragma unroll 1
  for (int kt = 0; kt < 32; kt += 2) {
    __syncthreads();                         // tile kt resident in buf0; buf1 reads done
    stage(1);                                // prefetch tile kt+1 (overlaps compute)
    compute(0);
    __syncthreads();                         // tile kt+1 resident in buf1; buf0 reads done
    if (kt + 2 < 32) stage(0);               // prefetch tile kt+2
    compute(1);
  }

  // epilogue: C/D layout col=lane&15, row=(lane>>4)*4+reg  [m89/m91-verified]
  const int region = bn >> 3;
  const int colb = (bn & 7) * 128 + wn * 64 + (lane & 15);
  const int row0 = bm * 128 + wm * 64 + ((lane >> 4) << 2);
  if (region == 0) {
#pragma unroll
    for (int i = 0; i < 4; i++)
#pragma unroll
      for (int j = 0; j < 4; j++)
#pragma unroll
        for (int rg = 0; rg < 4; rg++)
          Xt[(size_t)(row0 + i * 16 + rg) * 1024 + colb + j * 16] = f32_to_bf16(acc[i][j][rg]);
  } else {
    unsigned short* O = (region == 1) ? Fo : Ro;
    const float* bp = bias + (region - 1) * 1024;
#pragma unroll
    for (int j = 0; j < 4; j++) {
      float bb = bp[colb + j * 16];
#pragma unroll
      for (int i = 0; i < 4; i++)
#pragma unroll
        for (int rg = 0; rg < 4; rg++) {
          float s = sigmoidf_(acc[i][j][rg] + bb);
          O[(size_t)(row0 + i * 16 + rg) * 1024 + colb + j * 16] = f32_to_bf16(s);
        }
    }
  }
}

// -------------------------------------------------- blocked scan pass 1
__global__ void scan_pass1(const unsigned short* __restrict__ Xt, const unsigned short* __restrict__ F,
                           float* __restrict__ P, float* __restrict__ S) {
  int ch = blockIdx.x * blockDim.x + threadIdx.x;
  int chunk = blockIdx.y;
  size_t idx = (size_t)chunk * TCHUNK * NCH + ch;
  float p = 1.f, s = 0.f;
  for (int t = 0; t < TCHUNK; ++t) {
    float f  = bf16_to_f32(F[idx]);
    float xt = bf16_to_f32(Xt[idx]);
    s = f * s + (1.f - f) * xt;
    p *= f;
    idx += NCH;
  }
  P[(size_t)chunk * NCH + ch] = p;
  S[(size_t)chunk * NCH + ch] = s;
}

// -------------------------------------------------- serial combine -> carries
__global__ void combine_c0(const float* __restrict__ P, const float* __restrict__ S,
                           float* __restrict__ C0) {
  int ch = blockIdx.x * blockDim.x + threadIdx.x;
  float c = 0.f;
  for (int k = 0; k < NCHUNK; ++k) {
    C0[(size_t)k * NCH + ch] = c;
    c = P[(size_t)k * NCH + ch] * c + S[(size_t)k * NCH + ch];
  }
}

// -------- pass 2 (layer 1): h1 = r*c + (1-r)*x, row-major bf16 (coalesced) --
// x read from xsw (bf16): per-(t,wave) the gather hits one 1 KB chunk, L1-hot.
__global__ void scan1_pass2(const unsigned short* __restrict__ Xt, const unsigned short* __restrict__ F,
                            const unsigned short* __restrict__ R, const unsigned short* __restrict__ xsw,
                            const float* __restrict__ C0, unsigned short* __restrict__ h1b) {
  int ch = blockIdx.x * blockDim.x + threadIdx.x;
  int chunk = blockIdx.y;
  const int b = ch >> 10, h = ch & 1023;
  float c = C0[(size_t)chunk * NCH + ch];
  size_t idx = (size_t)chunk * TCHUNK * NCH + ch;
  const int hblk = h >> 5;
  const int lsub = ((h >> 3) & 3) * 16 + b;
  const int h7 = h & 7;
  for (int tt = 0; tt < TCHUNK; ++tt) {
    const int t = chunk * TCHUNK + tt;
    float f  = bf16_to_f32(F[idx]);
    float xt = bf16_to_f32(Xt[idx]);
    c = f * c + (1.f - f) * xt;
    float r  = bf16_to_f32(R[idx]);
    size_t soff = ((size_t)(t >> 3) * 32 + hblk) * 4096
                + (size_t)(((t & 7) * 64 + lsub) * 8 + h7);
    float xv = bf16_to_f32(xsw[soff]);
    h1b[idx] = f32_to_bf16(r * c + (1.f - r) * xv);
    idx += NCH;
  }
}

// ------- r2 at last timestep: (16x1024) @ W1[:,2048:3072] fp32, 64 blocks ---
__global__ void r2_kernel(const unsigned short* __restrict__ h1b, const float* __restrict__ W1,
                          const float* __restrict__ b1, float* __restrict__ r2) {
  __shared__ float xrow[1024];
  const int b = blockIdx.x, nq = blockIdx.y, tid = threadIdx.x;
  for (int i = tid; i < 1024; i += 256)
    xrow[i] = bf16_to_f32(h1b[(size_t)(2047 * 16 + b) * 1024 + i]);
  __syncthreads();
  const int n = nq * 256 + tid;
  float acc = b1[1024 + n];
  for (int d = 0; d < 1024; ++d)
    acc += xrow[d] * W1[(size_t)d * 3072 + 2048 + n];
  r2[b * 1024 + n] = sigmoidf_(acc);
}

// -------------------------------------------------- layer-2 combine + output
__global__ void combine_final(const float* __restrict__ P, const float* __restrict__ S,
                              const float* __restrict__ r2, const unsigned short* __restrict__ h1b,
                              float* __restrict__ out) {
  int ch = blockIdx.x * blockDim.x + threadIdx.x;
  float c = 0.f;
  for (int k = 0; k < NCHUNK; ++k)
    c = P[(size_t)k * NCH + ch] * c + S[(size_t)k * NCH + ch];
  float r = r2[ch];
  float x = bf16_to_f32(h1b[(size_t)2047 * NCH + ch]);
  out[ch] = r * c + (1.f - r) * x;
}

extern "C" void kernel_launch(void* const* d_in, const int* in_sizes, int n_in,
                              void* d_out, int out_size, void* d_ws, size_t ws_size,
                              hipStream_t stream) {
  const float* x  = (const float*)d_in[0];
  const float* W0 = (const float*)d_in[1];
  const float* b0 = (const float*)d_in[2];
  const float* W1 = (const float*)d_in[3];
  const float* b1 = (const float*)d_in[4];
  float* out = (float*)d_out;

  char* ws = (char*)d_ws;
  auto alloc = [&](size_t bytes) {
    char* p = ws; ws += (bytes + 255) & ~(size_t)255; return p;
  };
  const size_t NE = (size_t)M_TOT * HID;
  unsigned short* xsw   = (unsigned short*)alloc(NE * 2);            // x swizzled bf16
  unsigned short* W0sw  = (unsigned short*)alloc((size_t)3072 * 1024 * 2);
  unsigned short* W1sw  = (unsigned short*)alloc((size_t)3072 * 1024 * 2);
  unsigned short* Xt    = (unsigned short*)alloc(NE * 2);            // x_tilde bf16 row-major
  unsigned short* F     = (unsigned short*)alloc(NE * 2);            // f bf16 row-major
  unsigned short* R     = (unsigned short*)alloc(NE * 2);            // r bf16 (layer 1)
  unsigned short* h1b   = (unsigned short*)alloc(NE * 2);            // h1 row-major bf16
  unsigned short* h1sw  = (unsigned short*)alloc(NE * 2);            // h1 swizzled bf16
  float* P   = (float*)alloc((size_t)NCHUNK * NCH * 4);
  float* S   = (float*)alloc((size_t)NCHUNK * NCH * 4);
  float* C0  = (float*)alloc((size_t)NCHUNK * NCH * 4);
  float* r2  = (float*)alloc((size_t)NCH * 4);

  dim3 blk256(256);
  // 1. x -> swizzled bf16
  cast_swizzle_f32<<<dim3(M_TOT / 128, 32), blk256, 0, stream>>>(x, xsw, 1024);
  // 2. weights -> W^T swizzled bf16 (single pass each)
  w_prep<<<dim3(24, 32), blk256, 0, stream>>>(W0, W0sw);
  w_prep<<<dim3(24, 32), blk256, 0, stream>>>(W1, W1sw);
  // 3. layer-1 GEMM (N=3072), XCD + L2-group swizzled grid, dbuf K-loop
  gemm_sw_fused<<<dim3(24 * 256), blk256, 0, stream>>>(xsw, W0sw, Xt, F, R, b0, 24);
  // 4. blocked scan layer 1
  scan_pass1<<<dim3(NCH / 256, NCHUNK), blk256, 0, stream>>>(Xt, F, P, S);
  combine_c0<<<dim3(NCH / 256), blk256, 0, stream>>>(P, S, C0);
  scan1_pass2<<<dim3(NCH / 256, NCHUNK), blk256, 0, stream>>>(Xt, F, R, xsw, C0, h1b);
  // 5. h1 -> swizzled (coalesced both sides)
  swizzle_bf16<<<dim3(M_TOT / 128, 32), blk256, 0, stream>>>(h1b, h1sw, 1024);
  // 6. layer-2 GEMM (N=2048: x_tilde + f only)
  gemm_sw_fused<<<dim3(16 * 256), blk256, 0, stream>>>(h1sw, W1sw, Xt, F, R, b1, 16);
  // 7. r2 at last timestep
  r2_kernel<<<dim3(16, 4), blk256, 0, stream>>>(h1b, W1, b1, r2);
  // 8. blocked scan layer 2 (final c only) + output
  scan_pass1<<<dim3(NCH / 256, NCHUNK), blk256, 0, stream>>>(Xt, F, P, S);
  combine_final<<<dim3(NCH / 256), blk256, 0, stream>>>(P, S, r2, h1b, out);
}